// Round 6
// baseline (5075.661 us; speedup 1.0000x reference)
//
#include <hip/hip_runtime.h>
#include <cstdint>
#include <cstddef>

typedef unsigned short u16;
typedef unsigned int u32;
typedef unsigned long long u64;
typedef __attribute__((ext_vector_type(8))) short bfrag8;   // 8 bf16 = 4 VGPRs
typedef __attribute__((ext_vector_type(4))) float f32x4;

#define NB 64      // batch
#define NT 512     // timesteps
#define NE 256     // embedding dim
#define NH 512     // hidden dim
#define NWGW 128   // weight-staging workgroups (16 cols each, layout unchanged)
#define NBLK 64    // persistent compute blocks (32 cols each = 2 col-groups)
#define WSTR 408   // wlds per-lane stride in u16

__device__ __forceinline__ float bf2f(u16 b) { return __uint_as_float(((unsigned)b) << 16); }
__device__ __forceinline__ u16 f2bf(float f) {
  unsigned u = __float_as_uint(f);
  u += 0x7fffu + ((u >> 16) & 1u);   // round-to-nearest-even
  return (u16)(u >> 16);
}
__device__ __forceinline__ float fsigm(float x) { return 1.0f / (1.0f + __expf(-x)); }
__device__ __forceinline__ float ftanh(float x) { return 2.0f / (1.0f + __expf(-2.0f * x)) - 1.0f; }

// split fp32 -> (hi, lo) bf16 pair; hi + lo == v to ~2^-18 relative
__device__ __forceinline__ void split1(float v, u16& h, u16& l) {
  h = f2bf(v);
  float r = v - bf2f(h);
  l = f2bf(r);
}
__device__ __forceinline__ void split8(const float* p, bfrag8& hi, bfrag8& lo) {
#pragma unroll
  for (int i = 0; i < 8; ++i) {
    u16 h, l; split1(p[i], h, l);
    hi[i] = (short)h; lo[i] = (short)l;
  }
}

__device__ __forceinline__ void unpack8(uint4 q, float* o) {
  o[0] = __uint_as_float(q.x << 16); o[1] = __uint_as_float(q.x & 0xffff0000u);
  o[2] = __uint_as_float(q.y << 16); o[3] = __uint_as_float(q.y & 0xffff0000u);
  o[4] = __uint_as_float(q.z << 16); o[5] = __uint_as_float(q.z & 0xffff0000u);
  o[6] = __uint_as_float(q.w << 16); o[7] = __uint_as_float(q.w & 0xffff0000u);
}

// ---- h exchange: TAGGED u64 elements, fragment-major, dense per-wave ----
// element = (t<<32) | hi<<16 | lo.  u64 index:
//   ((((buf*4 + w)*16 + kt)*4 + p)*64 + lane)*2 + s
// (row, col): w=row>>4, lane=((col>>3)&3)*16+(row&15), kt=col>>5,
//             p=(col&7)>>1, s=col&1.
// Consumer wave w lane L reads, per (kt,p), 2 consecutive u64 at
//   base + kt*512 + p*128  -> each wave-instruction covers dense 1KB.
// The tag rides in the same atomic store as the data: no drain, no slot,
// no fence -- the check is on the loaded registers themselves.
__device__ __forceinline__ void hloadC(u64 (&v)[16], const u64* hp, int kt0) {
#pragma unroll
  for (int k = 0; k < 2; ++k)
#pragma unroll
    for (int p = 0; p < 4; ++p)
#pragma unroll
      for (int s = 0; s < 2; ++s)
        v[k * 8 + p * 2 + s] =
            __hip_atomic_load(hp + (size_t)(kt0 + k) * 512 + p * 128 + s,
                              __ATOMIC_RELAXED, __HIP_MEMORY_SCOPE_AGENT);
}
__device__ __forceinline__ bool hokC(const u64 (&v)[16], u32 need) {
  u32 bad = 0;
#pragma unroll
  for (int i = 0; i < 16; ++i) bad |= ((u32)(v[i] >> 32)) ^ need;
  return __all((int)(bad == 0)) != 0;
}
__device__ __forceinline__ void hconsC(const u64 (&v)[16], int kt0,
                                       const u16* wl0, const u16* wl1,
                                       f32x4& acc0, f32x4& acc1) {
#pragma unroll
  for (int k = 0; k < 2; ++k) {
    const int kt = kt0 + k;
    bfrag8 ah, al;
#pragma unroll
    for (int j = 0; j < 8; ++j) {
      u32 w = (u32)v[k * 8 + j];
      ah[j] = (short)(w >> 16); al[j] = (short)(w & 0xffffu);
    }
    bfrag8 whh0 = *(const bfrag8*)(wl0 + kt * 8);
    bfrag8 whl0 = *(const bfrag8*)(wl0 + (16 + kt) * 8);
    bfrag8 whh1 = *(const bfrag8*)(wl1 + kt * 8);
    bfrag8 whl1 = *(const bfrag8*)(wl1 + (16 + kt) * 8);
    acc0 = __builtin_amdgcn_mfma_f32_16x16x32_bf16(ah, whh0, acc0, 0, 0, 0);
    acc1 = __builtin_amdgcn_mfma_f32_16x16x32_bf16(ah, whh1, acc1, 0, 0, 0);
    acc0 = __builtin_amdgcn_mfma_f32_16x16x32_bf16(al, whh0, acc0, 0, 0, 0);
    acc1 = __builtin_amdgcn_mfma_f32_16x16x32_bf16(al, whh1, acc1, 0, 0, 0);
    acc0 = __builtin_amdgcn_mfma_f32_16x16x32_bf16(ah, whl0, acc0, 0, 0, 0);
    acc1 = __builtin_amdgcn_mfma_f32_16x16x32_bf16(ah, whl1, acc1, 0, 0, 0);
  }
}

// ---------------- prologue: pre-split weights into per-lane fragment layout ----
__global__ __launch_bounds__(64) void stage_weights(
    const float* __restrict__ Whr, const float* __restrict__ Whf,
    const float* __restrict__ Whg, const float* __restrict__ Who,
    const float* __restrict__ Wir, const float* __restrict__ Wif,
    const float* __restrict__ Wig, const float* __restrict__ Wio,
    const float* __restrict__ bhr, const float* __restrict__ bhf,
    const float* __restrict__ bhg, const float* __restrict__ bho,
    const float* __restrict__ bir, const float* __restrict__ bif,
    const float* __restrict__ big_, const float* __restrict__ bio,
    u16* __restrict__ wbuf, float* __restrict__ bias_s)
{
  const int wg = blockIdx.x;
  const int lane = threadIdx.x;
  const int colq = lane & 15;
  const int koff = (lane >> 4) * 8;
  const int gate = colq >> 2;
  const int gu = wg * 4 + (colq & 3);
  const float* wh = (gate == 0) ? Whr : (gate == 1) ? Whf : (gate == 2) ? Whg : Who;
  const float* wi = (gate == 0) ? Wir : (gate == 1) ? Wif : (gate == 2) ? Wig : Wio;
  u16* wb = wbuf + (size_t)(wg * 64 + lane) * 48 * 8;
  const float* whp = wh + (size_t)gu * NH + koff;
  const float* wip = wi + (size_t)gu * NE + koff;
#pragma unroll
  for (int kt = 0; kt < 16; ++kt) {
    bfrag8 hi, lo; split8(whp + kt * 32, hi, lo);
    *(bfrag8*)(wb + kt * 8) = hi;
    *(bfrag8*)(wb + (16 + kt) * 8) = lo;
  }
#pragma unroll
  for (int kt = 0; kt < 8; ++kt) {
    bfrag8 hi, lo; split8(wip + kt * 32, hi, lo);
    *(bfrag8*)(wb + (32 + kt) * 8) = hi;
    *(bfrag8*)(wb + (40 + kt) * 8) = lo;
  }
  if (lane < 16) {
    int g2 = lane >> 2, u2 = lane & 3, gu2 = wg * 4 + u2;
    const float* bh = (g2 == 0) ? bhr : (g2 == 1) ? bhf : (g2 == 2) ? bhg : bho;
    const float* bi = (g2 == 0) ? bir : (g2 == 1) ? bif : (g2 == 2) ? big_ : bio;
    bias_s[wg * 16 + lane] = bh[gu2] + bi[gu2];
  }
}

// ---------------- persistent LSTM: all 512 steps, wave-autonomous ----------
// No syncthreads/fences/slots in the loop. Wave w of block g:
//  - produces its 8 cols x 16 rows as TAGGED u64 stores (fire-and-forget;
//    critical path ends at store issue),
//  - consumes wave-w rows via 8 chunks (2 kt each) of dense tagged loads,
//    issued 4 deep ahead; a chunk is consumed when all 32 tags == t-1,
//    else that chunk alone is re-loaded (s_sleep backoff).
// Buffer-parity WAR safety is transitive: block at step t+1 has seen all
// peers' t tags => every peer consumed t-1 => overwriting parity (t-1)&1
// is safe. Math & accumulation order bit-identical to round 5.
__global__ __launch_bounds__(256, 1) void lstm_persist(
    const int* __restrict__ words,
    const float* __restrict__ emb,
    const u16* __restrict__ wbuf,
    const float* __restrict__ bias_s,
    u64* __restrict__ hbuf3,    // [2][4][16][4][64][2] tagged u64
    u16* __restrict__ hs_all,   // [T][B][H] bf16 (attention path, cached)
    float* __restrict__ hlast)  // [B][H] fp32 final h
{
  const int wg = blockIdx.x;                // 0..63
  const int tid = threadIdx.x;
  const int lane = tid & 63;
  const int wave = tid >> 6;
  const int mbase = wave * 16;
  const int colq = lane & 15;
  const int koff = (lane >> 4) * 8;
  const int arow = mbase + colq;            // batch row for A fragments

  __shared__ u16 wlds[2 * 64 * WSTR];       // ~102KB weights (2 col-groups)
  __shared__ float gatesLds[NB * 33];       // per-wave disjoint rows
  __shared__ float biasLds[32];

  if (wave < 2) {
    const u16* src = wbuf + (size_t)((wg * 2 + wave) * 64 + lane) * 384;
    u16* dst = wlds + (size_t)(wave * 64 + lane) * WSTR;
#pragma unroll
    for (int i = 0; i < 48; ++i)
      *(bfrag8*)(dst + i * 8) = *(const bfrag8*)(src + i * 8);
  }
  if (tid < 32) biasLds[tid] = bias_s[wg * 32 + tid];
  __syncthreads();

  const bool is64 = ((words[1] | words[3] | words[5] | words[7]) == 0);
  const int b_own = tid >> 2, u_own = tid & 3;
  float creg0 = 0.0f, creg1 = 0.0f;         // cell states: register-resident

  // producer store base (u64 units, without buffer-parity term)
  const size_t pslab = ((size_t)(b_own >> 4) * 16 + (wg >> 2)) * 512
                     + (size_t)(u_own >> 1) * 128
                     + (size_t)((wg & 3) * 16 + (b_own & 15)) * 2 + (u_own & 1);

  // preamble: emb gather for t=1 (normal cached loads; L2 stays warm)
  f32x4 xa[8], xb[8];
  {
    int widx = arow * NT + 0;
    int w = is64 ? words[2 * widx] : words[widx];
    const float* xs = emb + (size_t)w * NE + koff;
#pragma unroll
    for (int kt = 0; kt < 8; ++kt) {
      xa[kt] = *(const f32x4*)(xs + kt * 32);
      xb[kt] = *(const f32x4*)(xs + kt * 32 + 4);
    }
  }

  const u16* wl0 = wlds + (size_t)lane * WSTR;
  const u16* wl1 = wlds + (size_t)(64 + lane) * WSTR;

  for (int t = 1; t <= NT; ++t) {
    // ---- split emb once (A-side work, shared by both col-groups) ----
    bfrag8 xh[8], xl[8];
#pragma unroll
    for (int kt = 0; kt < 8; ++kt) {
#pragma unroll
      for (int i = 0; i < 4; ++i) {
        u16 h, l;
        split1(xa[kt][i], h, l); xh[kt][i] = (short)h;     xl[kt][i] = (short)l;
        split1(xb[kt][i], h, l); xh[kt][4 + i] = (short)h; xl[kt][4 + i] = (short)l;
      }
    }

    // ---- emb prefetch for t+1: early issue, drains whenever (no waits) ----
    if (t < NT) {
      int widx = arow * NT + t;
      int w = is64 ? words[2 * widx] : words[widx];
      const float* xs = emb + (size_t)w * NE + koff;
#pragma unroll
      for (int kt = 0; kt < 8; ++kt) {
        xa[kt] = *(const f32x4*)(xs + kt * 32);
        xb[kt] = *(const f32x4*)(xs + kt * 32 + 4);
      }
    }

    f32x4 acc0 = {0.f, 0.f, 0.f, 0.f};
    f32x4 acc1 = {0.f, 0.f, 0.f, 0.f};

    const u64* hp = hbuf3 + (size_t)((t - 1) & 1) * 32768
                  + (size_t)wave * 8192 + (size_t)lane * 2;
    const u32 need = (u32)(t - 1);
    u64 q0[16], q1[16], q2[16], q3[16];

    // ---- issue first 4 h chunks; X MFMAs below cover their latency ----
    if (t > 1) {
      hloadC(q0, hp, 0); hloadC(q1, hp, 2);
      hloadC(q2, hp, 4); hloadC(q3, hp, 6);
    }

    // ---- X MFMAs, col-group 0 then 1 (per-acc order identical to r5) ----
#pragma unroll
    for (int kt = 0; kt < 8; ++kt) {
      bfrag8 wih = *(const bfrag8*)(wl0 + (32 + kt) * 8);
      bfrag8 wil = *(const bfrag8*)(wl0 + (40 + kt) * 8);
      acc0 = __builtin_amdgcn_mfma_f32_16x16x32_bf16(xh[kt], wih, acc0, 0, 0, 0);
      acc0 = __builtin_amdgcn_mfma_f32_16x16x32_bf16(xl[kt], wih, acc0, 0, 0, 0);
      acc0 = __builtin_amdgcn_mfma_f32_16x16x32_bf16(xh[kt], wil, acc0, 0, 0, 0);
    }
#pragma unroll
    for (int kt = 0; kt < 8; ++kt) {
      bfrag8 wih = *(const bfrag8*)(wl1 + (32 + kt) * 8);
      bfrag8 wil = *(const bfrag8*)(wl1 + (40 + kt) * 8);
      acc1 = __builtin_amdgcn_mfma_f32_16x16x32_bf16(xh[kt], wih, acc1, 0, 0, 0);
      acc1 = __builtin_amdgcn_mfma_f32_16x16x32_bf16(xl[kt], wih, acc1, 0, 0, 0);
      acc1 = __builtin_amdgcn_mfma_f32_16x16x32_bf16(xh[kt], wil, acc1, 0, 0, 0);
    }

    // ---- h phase: check-tag / consume / refill, 4-deep pipeline ----
    if (t > 1) {
      while (!hokC(q0, need)) { __builtin_amdgcn_s_sleep(1); hloadC(q0, hp, 0); }
      hconsC(q0, 0, wl0, wl1, acc0, acc1);
      hloadC(q0, hp, 8);
      while (!hokC(q1, need)) { __builtin_amdgcn_s_sleep(1); hloadC(q1, hp, 2); }
      hconsC(q1, 2, wl0, wl1, acc0, acc1);
      hloadC(q1, hp, 10);
      while (!hokC(q2, need)) { __builtin_amdgcn_s_sleep(1); hloadC(q2, hp, 4); }
      hconsC(q2, 4, wl0, wl1, acc0, acc1);
      hloadC(q2, hp, 12);
      while (!hokC(q3, need)) { __builtin_amdgcn_s_sleep(1); hloadC(q3, hp, 6); }
      hconsC(q3, 6, wl0, wl1, acc0, acc1);
      hloadC(q3, hp, 14);
      while (!hokC(q0, need)) { __builtin_amdgcn_s_sleep(1); hloadC(q0, hp, 8); }
      hconsC(q0, 8, wl0, wl1, acc0, acc1);
      while (!hokC(q1, need)) { __builtin_amdgcn_s_sleep(1); hloadC(q1, hp, 10); }
      hconsC(q1, 10, wl0, wl1, acc0, acc1);
      while (!hokC(q2, need)) { __builtin_amdgcn_s_sleep(1); hloadC(q2, hp, 12); }
      hconsC(q2, 12, wl0, wl1, acc0, acc1);
      while (!hokC(q3, need)) { __builtin_amdgcn_s_sleep(1); hloadC(q3, hp, 14); }
      hconsC(q3, 14, wl0, wl1, acc0, acc1);
    }

    // ---- intra-wave transpose via LDS (wave's own rows; no barrier) ----
    {
      int drow = mbase + ((lane >> 4) << 2);
#pragma unroll
      for (int r = 0; r < 4; ++r) {
        gatesLds[(drow + r) * 33 + colq] = acc0[r];
        gatesLds[(drow + r) * 33 + 16 + colq] = acc1[r];
      }
    }

    // ---- gate math; thread owns (b_own, u_own) in both col-groups ----
    {
      const float* gl = &gatesLds[b_own * 33];
      float xr = gl[u_own]      + biasLds[u_own];
      float xf = gl[4 + u_own]  + biasLds[4 + u_own];
      float xg = gl[8 + u_own]  + biasLds[8 + u_own];
      float xo = gl[12 + u_own] + biasLds[12 + u_own];
      float rg = fsigm(xr), fg = fsigm(xf), gg = ftanh(xg), og = fsigm(xo);
      creg0 = fg * creg0 + rg * gg;
      float hv0 = og * ftanh(creg0);
      float yr = gl[16 + u_own] + biasLds[16 + u_own];
      float yf = gl[20 + u_own] + biasLds[20 + u_own];
      float yg = gl[24 + u_own] + biasLds[24 + u_own];
      float yo = gl[28 + u_own] + biasLds[28 + u_own];
      float rh = fsigm(yr), fh2 = fsigm(yf), gh = ftanh(yg), oh = fsigm(yo);
      creg1 = fh2 * creg1 + rh * gh;
      float hv1 = oh * ftanh(creg1);

      u16 h0h, h0l, h1h, h1l;
      split1(hv0, h0h, h0l);
      split1(hv1, h1h, h1l);
      // tagged stores FIRST (these are the step's announcement)
      u64* pb = hbuf3 + (size_t)(t & 1) * 32768 + pslab;
      u64 e0 = ((u64)(u32)t << 32) | ((u32)h0h << 16) | (u32)h0l;
      u64 e1 = ((u64)(u32)t << 32) | ((u32)h1h << 16) | (u32)h1l;
      __hip_atomic_store(pb,       e0, __ATOMIC_RELAXED, __HIP_MEMORY_SCOPE_AGENT);
      __hip_atomic_store(pb + 256, e1, __ATOMIC_RELAXED, __HIP_MEMORY_SCOPE_AGENT);
      int col0 = wg * 8 + u_own, col1 = col0 + 4;
      size_t hsb = (size_t)(t - 1) * (NB * NH) + (size_t)b_own * NH;
      hs_all[hsb + col0] = h0h;
      hs_all[hsb + col1] = h1h;
      if (t == NT) {
        hlast[b_own * NH + col0] = hv0;
        hlast[b_own * NH + col1] = hv1;
      }
    }
    // no drain, no slot post, no fence: tags carry the handshake
  }
}

// ---------------- attention + output head (one WG per batch) ----------------
__global__ __launch_bounds__(256) void post_kernel(
    const float* __restrict__ hlast,  // [B][H] fp32
    const u16* __restrict__ hs,       // [T][B][H] bf16
    const float* __restrict__ W_ol, const float* __restrict__ b_ol,   // [256][512], [256]
    const float* __restrict__ W_att, const float* __restrict__ b_att, // [256][512], [512]
    const float* __restrict__ W_fc, const float* __restrict__ b_fc,   // [2][768], [2]
    float* __restrict__ out)          // [64*2] ++ [64*512] fp32
{
  int b = blockIdx.x, tid = threadIdx.x;
  __shared__ float hl[NH], fh[256], sc[NH], att[NT], ao[NH], red[256];

  for (int i = tid; i < NH; i += 256) {
    float hv = hlast[b * NH + i];
    hl[i] = hv;
    out[128 + b * NH + i] = hv;   // output 1: h_last
  }
  __syncthreads();

  // final_hidden[j] = b_ol[j] + hl . W_ol[j][:]
  {
    float s = b_ol[tid];
    const float* w = W_ol + (size_t)tid * NH;
    for (int k = 0; k < NH; k += 4) {
      f32x4 q = *(const f32x4*)(w + k);
      s += q[0] * hl[k] + q[1] * hl[k + 1] + q[2] * hl[k + 2] + q[3] * hl[k + 3];
    }
    fh[tid] = s;
  }
  __syncthreads();

  // score[h] = b_att[h] + sum_j fh[j] * W_att[j][h]
  for (int h = tid; h < NH; h += 256) {
    float s = b_att[h];
    for (int j = 0; j < 256; ++j) s += fh[j] * W_att[(size_t)j * NH + h];
    sc[h] = s;
  }
  __syncthreads();

  // att[t] = score . hs[t][b][:]
  for (int t = tid; t < NT; t += 256) {
    const u16* row = hs + ((size_t)t * NB + b) * NH;
    float s = 0.f;
    for (int k = 0; k < NH; k += 8) {
      uint4 q = *(const uint4*)(row + k);
      float tmp[8]; unpack8(q, tmp);
#pragma unroll
      for (int j = 0; j < 8; ++j) s += tmp[j] * sc[k + j];
    }
    att[t] = s;
  }
  __syncthreads();

  // softmax over T
  float l0 = att[tid], l1 = att[tid + 256];
  red[tid] = fmaxf(l0, l1);
  __syncthreads();
  for (int s = 128; s > 0; s >>= 1) { if (tid < s) red[tid] = fmaxf(red[tid], red[tid + s]); __syncthreads(); }
  float mx = red[0];
  __syncthreads();
  float e0 = __expf(l0 - mx), e1 = __expf(l1 - mx);
  red[tid] = e0 + e1;
  __syncthreads();
  for (int s = 128; s > 0; s >>= 1) { if (tid < s) red[tid] += red[tid + s]; __syncthreads(); }
  float inv = 1.0f / red[0];
  __syncthreads();
  att[tid] = e0 * inv;
  att[tid + 256] = e1 * inv;
  __syncthreads();

  // att_out[h] = sum_t dist[t] * hs[t][b][h]
  {
    float a0 = 0.f, a1 = 0.f;
    for (int t = 0; t < NT; ++t) {
      float d = att[t];
      const u16* row = hs + ((size_t)t * NB + b) * NH;
      a0 += d * bf2f(row[tid]);
      a1 += d * bf2f(row[tid + 256]);
    }
    ao[tid] = a0;
    ao[tid + 256] = a1;
  }
  __syncthreads();

  // out[o] = sigmoid(b_fc[o] + [fh, ao] . W_fc[o][:])
#pragma unroll
  for (int o = 0; o < 2; ++o) {
    float part = 0.f;
    for (int i = tid; i < 768; i += 256) {
      float v = (i < 256) ? fh[i] : ao[i - 256];
      part += v * W_fc[o * 768 + i];
    }
    red[tid] = part;
    __syncthreads();
    for (int s = 128; s > 0; s >>= 1) { if (tid < s) red[tid] += red[tid + s]; __syncthreads(); }
    if (tid == 0) out[b * 2 + o] = fsigm(red[0] + b_fc[o]);
    __syncthreads();
  }
}

// ---------------- host launch: memset(hbuf3) + stage + persist + post ------
extern "C" void kernel_launch(void* const* d_in, const int* in_sizes, int n_in,
                              void* d_out, int out_size, void* d_ws, size_t ws_size,
                              hipStream_t stream) {
  const int* words  = (const int*)d_in[0];
  const float* emb  = (const float*)d_in[1];
  const float* Wir  = (const float*)d_in[2];  const float* bir = (const float*)d_in[3];
  const float* Whr  = (const float*)d_in[4];  const float* bhr = (const float*)d_in[5];
  const float* Wif  = (const float*)d_in[6];  const float* bif = (const float*)d_in[7];
  const float* Whf  = (const float*)d_in[8];  const float* bhf = (const float*)d_in[9];
  const float* Wig  = (const float*)d_in[10]; const float* big_ = (const float*)d_in[11];
  const float* Whg  = (const float*)d_in[12]; const float* bhg = (const float*)d_in[13];
  const float* Wio  = (const float*)d_in[14]; const float* bio = (const float*)d_in[15];
  const float* Who  = (const float*)d_in[16]; const float* bho = (const float*)d_in[17];
  const float* W_att = (const float*)d_in[18]; const float* b_att = (const float*)d_in[19];
  const float* W_ol  = (const float*)d_in[20]; const float* b_ol  = (const float*)d_in[21];
  const float* W_fc  = (const float*)d_in[22]; const float* b_fc  = (const float*)d_in[23];

  uint8_t* ws = (uint8_t*)d_ws;
  u16* hs       = (u16*)ws;                              // 512*64*512*2 = 32 MiB
  size_t off    = (size_t)33554432;
  u16* wbuf     = (u16*)(ws + off);   off += 6291456;    // 128*64*48*16B = 6 MiB
  float* bias_s = (float*)(ws + off); off += 8192;       // 128*16*4
  u64* hbuf3    = (u64*)(ws + off);   off += 524288;     // 2*4*16*4*64*2*8B tagged
  float* hlast  = (float*)(ws + off);                    // 64*512*4

  // zero all tags every launch/replay: prevents stale-tag false-match
  hipMemsetAsync(hbuf3, 0, 524288, stream);

  stage_weights<<<dim3(NWGW), dim3(64), 0, stream>>>(
      Whr, Whf, Whg, Who, Wir, Wif, Wig, Wio,
      bhr, bhf, bhg, bho, bir, bif, big_, bio, wbuf, bias_s);

  lstm_persist<<<dim3(NBLK), dim3(256), 0, stream>>>(
      words, emb, wbuf, bias_s, hbuf3, hs, hlast);

  post_kernel<<<dim3(NB), dim3(256), 0, stream>>>(hlast, hs, W_ol, b_ol, W_att, b_att,
                                                  W_fc, b_fc, (float*)d_out);
}

// Round 7
// 1632.347 us; speedup vs baseline: 3.1094x; 3.1094x over previous
//
#include <hip/hip_runtime.h>
#include <cstdint>
#include <cstddef>

typedef unsigned short u16;
typedef unsigned int u32;
typedef unsigned long long u64;
typedef __attribute__((ext_vector_type(8))) short bfrag8;   // 8 bf16 = 4 VGPRs
typedef __attribute__((ext_vector_type(4))) float f32x4;

#define NB 64      // batch
#define NT 512     // timesteps
#define NE 256     // embedding dim
#define NH 512     // hidden dim
#define NWGW 128   // weight-staging workgroups (16 cols each, layout unchanged)
#define NBLK 256   // persistent blocks: 4 batch-groups x 64 col-blocks
#define WSTR 408   // wlds per-lane stride in u16

__device__ __forceinline__ float bf2f(u16 b) { return __uint_as_float(((unsigned)b) << 16); }
__device__ __forceinline__ u16 f2bf(float f) {
  unsigned u = __float_as_uint(f);
  u += 0x7fffu + ((u >> 16) & 1u);   // round-to-nearest-even
  return (u16)(u >> 16);
}
__device__ __forceinline__ float fsigm(float x) { return 1.0f / (1.0f + __expf(-x)); }
__device__ __forceinline__ float ftanh(float x) { return 2.0f / (1.0f + __expf(-2.0f * x)) - 1.0f; }

// split fp32 -> (hi, lo) bf16 pair; hi + lo == v to ~2^-18 relative
__device__ __forceinline__ void split1(float v, u16& h, u16& l) {
  h = f2bf(v);
  float r = v - bf2f(h);
  l = f2bf(r);
}
__device__ __forceinline__ void split8(const float* p, bfrag8& hi, bfrag8& lo) {
#pragma unroll
  for (int i = 0; i < 8; ++i) {
    u16 h, l; split1(p[i], h, l);
    hi[i] = (short)h; lo[i] = (short)l;
  }
}

__device__ __forceinline__ void unpack8(uint4 q, float* o) {
  o[0] = __uint_as_float(q.x << 16); o[1] = __uint_as_float(q.x & 0xffff0000u);
  o[2] = __uint_as_float(q.y << 16); o[3] = __uint_as_float(q.y & 0xffff0000u);
  o[4] = __uint_as_float(q.z << 16); o[5] = __uint_as_float(q.z & 0xffff0000u);
  o[6] = __uint_as_float(q.w << 16); o[7] = __uint_as_float(q.w & 0xffff0000u);
}

// ---------------- prologue: pre-split weights into per-lane fragment layout ----
// Layout unchanged: wbuf[wg<128][lane<64][48] bfrag8. Compute block (G,ib)
// consumes wg = {2ib, 2ib+1}; its waves index kt-subsets of the same image.
__global__ __launch_bounds__(64) void stage_weights(
    const float* __restrict__ Whr, const float* __restrict__ Whf,
    const float* __restrict__ Whg, const float* __restrict__ Who,
    const float* __restrict__ Wir, const float* __restrict__ Wif,
    const float* __restrict__ Wig, const float* __restrict__ Wio,
    const float* __restrict__ bhr, const float* __restrict__ bhf,
    const float* __restrict__ bhg, const float* __restrict__ bho,
    const float* __restrict__ bir, const float* __restrict__ bif,
    const float* __restrict__ big_, const float* __restrict__ bio,
    u16* __restrict__ wbuf, float* __restrict__ bias_s)
{
  const int wg = blockIdx.x;
  const int lane = threadIdx.x;
  const int colq = lane & 15;
  const int koff = (lane >> 4) * 8;
  const int gate = colq >> 2;
  const int gu = wg * 4 + (colq & 3);
  const float* wh = (gate == 0) ? Whr : (gate == 1) ? Whf : (gate == 2) ? Whg : Who;
  const float* wi = (gate == 0) ? Wir : (gate == 1) ? Wif : (gate == 2) ? Wig : Wio;
  u16* wb = wbuf + (size_t)(wg * 64 + lane) * 48 * 8;
  const float* whp = wh + (size_t)gu * NH + koff;
  const float* wip = wi + (size_t)gu * NE + koff;
#pragma unroll
  for (int kt = 0; kt < 16; ++kt) {
    bfrag8 hi, lo; split8(whp + kt * 32, hi, lo);
    *(bfrag8*)(wb + kt * 8) = hi;
    *(bfrag8*)(wb + (16 + kt) * 8) = lo;
  }
#pragma unroll
  for (int kt = 0; kt < 8; ++kt) {
    bfrag8 hi, lo; split8(wip + kt * 32, hi, lo);
    *(bfrag8*)(wb + (32 + kt) * 8) = hi;
    *(bfrag8*)(wb + (40 + kt) * 8) = lo;
  }
  if (lane < 16) {
    int g2 = lane >> 2, u2 = lane & 3, gu2 = wg * 4 + u2;
    const float* bh = (g2 == 0) ? bhr : (g2 == 1) ? bhf : (g2 == 2) ? bhg : bho;
    const float* bi = (g2 == 0) ? bir : (g2 == 1) ? bif : (g2 == 2) ? big_ : bio;
    bias_s[wg * 16 + lane] = bh[gu2] + bi[gu2];
  }
}

// ---------------- persistent LSTM: 256 blocks = 4 batch-groups x 64 ----------
// Batch rows are recurrence-independent: group G (blockIdx>>6) owns rows
// [16G,16G+16) end-to-end; groups never sync with each other. Block (G,ib)
// computes gate-cols [32ib,32ib+32) (units [8ib,8ib+8)) for its 16 rows.
// The K reduction is split over the 4 waves (wave w: h-kt {4w..4w+4},
// X-kt {2w..2w+2}); partials combine in LDS, then tid<128 do gate math.
// h exchange (within group only): fragment-major u64 slab
//   hbuf[buf][G][w][ktl][p][lane] : element (row 16G+(lane&15),
//   col 128w+32ktl+(lane>>4)*8+2p+s) packed (hi<<16|lo) in u32 s of the u64.
// Producer posts slot[G][ib]=t after sync2 (implicit vmcnt(0) drain);
// consumer wave w polls its 16 producers' slots then loads 16 dense u64.
// WAR safe: block reaches t only after all group peers posted t-1, which is
// after they consumed t-2 => parity buffer overwrite is safe.
__global__ __launch_bounds__(256, 1) void lstm_persist(
    const int* __restrict__ words,
    const float* __restrict__ emb,
    const u16* __restrict__ wbuf,
    const float* __restrict__ bias_s,
    u64* __restrict__ hbuf,     // [2][4][4][4][4][64] u64 fragment-major
    u16* __restrict__ hs_all,   // [T][B][H] bf16 (attention path, cached)
    float* __restrict__ hlast,  // [B][H] fp32 final h
    u32* __restrict__ slots)    // [4][64] step counters, 64B stride
{
  const int G    = blockIdx.x >> 6;         // batch group 0..3
  const int ib   = blockIdx.x & 63;         // col-block 0..63
  const int tid  = threadIdx.x;
  const int lane = tid & 63;
  const int wave = tid >> 6;                // K-slice 0..3
  const int colq = lane & 15;
  const int koff = (lane >> 4) * 8;
  const int arow = 16 * G + colq;           // batch row for A fragments

  __shared__ u16 wlds[2 * 64 * WSTR];       // ~102KB weights (2 col-groups)
  __shared__ float pl[4 * 16 * 34];         // K-partials [w][row][32+pad]
  __shared__ float biasLds[32];

  if (wave < 2) {
    const u16* src = wbuf + (size_t)((ib * 2 + wave) * 64 + lane) * 384;
    u16* dst = wlds + (size_t)(wave * 64 + lane) * WSTR;
#pragma unroll
    for (int i = 0; i < 48; ++i)
      *(bfrag8*)(dst + i * 8) = *(const bfrag8*)(src + i * 8);
  }
  if (tid < 32) biasLds[tid] = bias_s[ib * 32 + tid];
  __syncthreads();

  const bool is64 = ((words[1] | words[3] | words[5] | words[7]) == 0);
  const int r_loc = tid >> 3;               // gate-phase row (tid<128)
  const int uo    = tid & 7;                // gate-phase unit offset
  float creg = 0.0f;                        // one cell state per gate thread

  // preamble: emb gather for t=1 (wave w loads its X k-slice only)
  f32x4 xa[2], xb[2];
  {
    int widx = arow * NT + 0;
    int wd = is64 ? words[2 * widx] : words[widx];
    const float* xs = emb + (size_t)wd * NE + wave * 64 + koff;
    xa[0] = *(const f32x4*)(xs);      xb[0] = *(const f32x4*)(xs + 4);
    xa[1] = *(const f32x4*)(xs + 32); xb[1] = *(const f32x4*)(xs + 36);
  }

  const u16* wl0 = wlds + (size_t)lane * WSTR;
  const u16* wl1 = wlds + (size_t)(64 + lane) * WSTR;
  // producer u64 slot (sans buffer-parity term); valid for tid<128, uo even
  const size_t pstore = (size_t)G * 4096 + (size_t)(ib >> 4) * 1024
                      + (size_t)((ib >> 2) & 3) * 256 + (size_t)(uo >> 1) * 64
                      + (size_t)((ib & 3) * 16 + r_loc);
  u32* postp = slots + (G * 64 + ib) * 16;
  const u32* pollp = slots + (G * 64 + 16 * wave + colq) * 16;

  for (int t = 1; t <= NT; ++t) {
    // ---- split this step's emb slice (shared by both col-groups) ----
    bfrag8 xh[2], xl[2];
#pragma unroll
    for (int xt = 0; xt < 2; ++xt)
#pragma unroll
      for (int i = 0; i < 4; ++i) {
        u16 h, l;
        split1(xa[xt][i], h, l); xh[xt][i] = (short)h;     xl[xt][i] = (short)l;
        split1(xb[xt][i], h, l); xh[xt][4 + i] = (short)h; xl[xt][4 + i] = (short)l;
      }

    // ---- emb prefetch t+1 (drains under this step's MFMAs/waits) ----
    if (t < NT) {
      int widx = arow * NT + t;
      int wd = is64 ? words[2 * widx] : words[widx];
      const float* xs = emb + (size_t)wd * NE + wave * 64 + koff;
      xa[0] = *(const f32x4*)(xs);      xb[0] = *(const f32x4*)(xs + 4);
      xa[1] = *(const f32x4*)(xs + 32); xb[1] = *(const f32x4*)(xs + 36);
    }

    f32x4 acc0 = {0.f, 0.f, 0.f, 0.f};
    f32x4 acc1 = {0.f, 0.f, 0.f, 0.f};

    // ---- X MFMAs for this wave's k-slice (covers producer lag) ----
#pragma unroll
    for (int xt = 0; xt < 2; ++xt) {
      int f = 2 * wave + xt;
      bfrag8 wih = *(const bfrag8*)(wl0 + (32 + f) * 8);
      bfrag8 wil = *(const bfrag8*)(wl0 + (40 + f) * 8);
      acc0 = __builtin_amdgcn_mfma_f32_16x16x32_bf16(xh[xt], wih, acc0, 0, 0, 0);
      acc0 = __builtin_amdgcn_mfma_f32_16x16x32_bf16(xl[xt], wih, acc0, 0, 0, 0);
      acc0 = __builtin_amdgcn_mfma_f32_16x16x32_bf16(xh[xt], wil, acc0, 0, 0, 0);
    }
#pragma unroll
    for (int xt = 0; xt < 2; ++xt) {
      int f = 2 * wave + xt;
      bfrag8 wih = *(const bfrag8*)(wl1 + (32 + f) * 8);
      bfrag8 wil = *(const bfrag8*)(wl1 + (40 + f) * 8);
      acc1 = __builtin_amdgcn_mfma_f32_16x16x32_bf16(xh[xt], wih, acc1, 0, 0, 0);
      acc1 = __builtin_amdgcn_mfma_f32_16x16x32_bf16(xl[xt], wih, acc1, 0, 0, 0);
      acc1 = __builtin_amdgcn_mfma_f32_16x16x32_bf16(xh[xt], wil, acc1, 0, 0, 0);
    }

    // ---- h phase: poll my 16 producers, then 16 dense u64 loads ----
    if (t > 1) {
      const u32 need = (u32)(t - 1);
      u32 v;
      do {
        v = __hip_atomic_load(pollp, __ATOMIC_RELAXED, __HIP_MEMORY_SCOPE_AGENT);
      } while (!__all((int)(v >= need)));
      asm volatile("" ::: "memory");        // compiler fence: loads stay below

      const u64* hb = hbuf + ((size_t)(((t - 1) & 1) * 16 + G * 4 + wave)) * 1024 + lane;
      u64 q[16];
#pragma unroll
      for (int i = 0; i < 16; ++i)
        q[i] = __hip_atomic_load(hb + (size_t)i * 64, __ATOMIC_RELAXED, __HIP_MEMORY_SCOPE_AGENT);

#pragma unroll
      for (int ktl = 0; ktl < 4; ++ktl) {
        bfrag8 ah, al;
#pragma unroll
        for (int p = 0; p < 4; ++p) {
          u64 vq = q[ktl * 4 + p];
          u32 w0 = (u32)vq, w1 = (u32)(vq >> 32);
          ah[2 * p]     = (short)(w0 >> 16); al[2 * p]     = (short)(w0 & 0xffffu);
          ah[2 * p + 1] = (short)(w1 >> 16); al[2 * p + 1] = (short)(w1 & 0xffffu);
        }
        int f = 4 * wave + ktl;
        bfrag8 whh0 = *(const bfrag8*)(wl0 + f * 8);
        bfrag8 whl0 = *(const bfrag8*)(wl0 + (16 + f) * 8);
        bfrag8 whh1 = *(const bfrag8*)(wl1 + f * 8);
        bfrag8 whl1 = *(const bfrag8*)(wl1 + (16 + f) * 8);
        acc0 = __builtin_amdgcn_mfma_f32_16x16x32_bf16(ah, whh0, acc0, 0, 0, 0);
        acc1 = __builtin_amdgcn_mfma_f32_16x16x32_bf16(ah, whh1, acc1, 0, 0, 0);
        acc0 = __builtin_amdgcn_mfma_f32_16x16x32_bf16(al, whh0, acc0, 0, 0, 0);
        acc1 = __builtin_amdgcn_mfma_f32_16x16x32_bf16(al, whh1, acc1, 0, 0, 0);
        acc0 = __builtin_amdgcn_mfma_f32_16x16x32_bf16(ah, whl0, acc0, 0, 0, 0);
        acc1 = __builtin_amdgcn_mfma_f32_16x16x32_bf16(ah, whl1, acc1, 0, 0, 0);
      }
    }

    // ---- write K-partials to LDS ----
    {
      int rb = (lane >> 4) << 2;
#pragma unroll
      for (int r = 0; r < 4; ++r) {
        pl[(wave * 16 + rb + r) * 34 + colq] = acc0[r];
        pl[(wave * 16 + rb + r) * 34 + 16 + colq] = acc1[r];
      }
    }
    __syncthreads();                        // sync1: partials visible

    // ---- K-reduce + gate math: thread (r_loc, uo) owns unit 8ib+uo ----
    if (tid < 128) {
      int clb = ((uo >> 2) << 4) + (uo & 3);
      const float* pr = pl + r_loc * 34;
      float xr = biasLds[clb], xf = biasLds[clb + 4];
      float xg = biasLds[clb + 8], xo = biasLds[clb + 12];
#pragma unroll
      for (int w = 0; w < 4; ++w) {
        const float* pw = pr + w * 16 * 34;
        xr += pw[clb]; xf += pw[clb + 4]; xg += pw[clb + 8]; xo += pw[clb + 12];
      }
      float rg = fsigm(xr), fg = fsigm(xf), gg = ftanh(xg), og = fsigm(xo);
      creg = fg * creg + rg * gg;
      float hv = og * ftanh(creg);
      u16 hhi, hlo; split1(hv, hhi, hlo);
      u32 hval = ((u32)hhi << 16) | (u32)hlo;
      u32 pv = (u32)__shfl_xor((int)hval, 1);   // partner unit (uo^1)
      int grow = 16 * G + r_loc;
      int gcol = 8 * ib + uo;
      if ((uo & 1) == 0) {
        u64 e = (u64)hval | ((u64)pv << 32);
        __hip_atomic_store(hbuf + (size_t)(t & 1) * 16384 + pstore, e,
                           __ATOMIC_RELAXED, __HIP_MEMORY_SCOPE_AGENT);
        u32 hspack = (u32)hhi | (pv & 0xffff0000u);
        *(u32*)&hs_all[(size_t)(t - 1) * (NB * NH) + (size_t)grow * NH + gcol] = hspack;
      }
      if (t == NT) hlast[grow * NH + gcol] = hv;
    }

    // ---- sync2: implicit per-wave vmcnt(0) drains h stores, then post ----
    __syncthreads();
    if (tid == 0)
      __hip_atomic_store(postp, (u32)t, __ATOMIC_RELAXED, __HIP_MEMORY_SCOPE_AGENT);
  }
}

// ---------------- attention + output head (one WG per batch) ----------------
__global__ __launch_bounds__(256) void post_kernel(
    const float* __restrict__ hlast,  // [B][H] fp32
    const u16* __restrict__ hs,       // [T][B][H] bf16
    const float* __restrict__ W_ol, const float* __restrict__ b_ol,   // [256][512], [256]
    const float* __restrict__ W_att, const float* __restrict__ b_att, // [256][512], [512]
    const float* __restrict__ W_fc, const float* __restrict__ b_fc,   // [2][768], [2]
    float* __restrict__ out)          // [64*2] ++ [64*512] fp32
{
  int b = blockIdx.x, tid = threadIdx.x;
  __shared__ float hl[NH], fh[256], sc[NH], att[NT], ao[NH], red[256];

  for (int i = tid; i < NH; i += 256) {
    float hv = hlast[b * NH + i];
    hl[i] = hv;
    out[128 + b * NH + i] = hv;   // output 1: h_last
  }
  __syncthreads();

  // final_hidden[j] = b_ol[j] + hl . W_ol[j][:]
  {
    float s = b_ol[tid];
    const float* w = W_ol + (size_t)tid * NH;
    for (int k = 0; k < NH; k += 4) {
      f32x4 q = *(const f32x4*)(w + k);
      s += q[0] * hl[k] + q[1] * hl[k + 1] + q[2] * hl[k + 2] + q[3] * hl[k + 3];
    }
    fh[tid] = s;
  }
  __syncthreads();

  // score[h] = b_att[h] + sum_j fh[j] * W_att[j][h]
  for (int h = tid; h < NH; h += 256) {
    float s = b_att[h];
    for (int j = 0; j < 256; ++j) s += fh[j] * W_att[(size_t)j * NH + h];
    sc[h] = s;
  }
  __syncthreads();

  // att[t] = score . hs[t][b][:]
  for (int t = tid; t < NT; t += 256) {
    const u16* row = hs + ((size_t)t * NB + b) * NH;
    float s = 0.f;
    for (int k = 0; k < NH; k += 8) {
      uint4 q = *(const uint4*)(row + k);
      float tmp[8]; unpack8(q, tmp);
#pragma unroll
      for (int j = 0; j < 8; ++j) s += tmp[j] * sc[k + j];
    }
    att[t] = s;
  }
  __syncthreads();

  // softmax over T
  float l0 = att[tid], l1 = att[tid + 256];
  red[tid] = fmaxf(l0, l1);
  __syncthreads();
  for (int s = 128; s > 0; s >>= 1) { if (tid < s) red[tid] = fmaxf(red[tid], red[tid + s]); __syncthreads(); }
  float mx = red[0];
  __syncthreads();
  float e0 = __expf(l0 - mx), e1 = __expf(l1 - mx);
  red[tid] = e0 + e1;
  __syncthreads();
  for (int s = 128; s > 0; s >>= 1) { if (tid < s) red[tid] += red[tid + s]; __syncthreads(); }
  float inv = 1.0f / red[0];
  __syncthreads();
  att[tid] = e0 * inv;
  att[tid + 256] = e1 * inv;
  __syncthreads();

  // att_out[h] = sum_t dist[t] * hs[t][b][h]
  {
    float a0 = 0.f, a1 = 0.f;
    for (int t = 0; t < NT; ++t) {
      float d = att[t];
      const u16* row = hs + ((size_t)t * NB + b) * NH;
      a0 += d * bf2f(row[tid]);
      a1 += d * bf2f(row[tid + 256]);
    }
    ao[tid] = a0;
    ao[tid + 256] = a1;
  }
  __syncthreads();

  // out[o] = sigmoid(b_fc[o] + [fh, ao] . W_fc[o][:])
#pragma unroll
  for (int o = 0; o < 2; ++o) {
    float part = 0.f;
    for (int i = tid; i < 768; i += 256) {
      float v = (i < 256) ? fh[i] : ao[i - 256];
      part += v * W_fc[o * 768 + i];
    }
    red[tid] = part;
    __syncthreads();
    for (int s = 128; s > 0; s >>= 1) { if (tid < s) red[tid] += red[tid + s]; __syncthreads(); }
    if (tid == 0) out[b * 2 + o] = fsigm(red[0] + b_fc[o]);
    __syncthreads();
  }
}

// ---------------- host launch: memset(slots) + stage + persist + post ------
extern "C" void kernel_launch(void* const* d_in, const int* in_sizes, int n_in,
                              void* d_out, int out_size, void* d_ws, size_t ws_size,
                              hipStream_t stream) {
  const int* words  = (const int*)d_in[0];
  const float* emb  = (const float*)d_in[1];
  const float* Wir  = (const float*)d_in[2];  const float* bir = (const float*)d_in[3];
  const float* Whr  = (const float*)d_in[4];  const float* bhr = (const float*)d_in[5];
  const float* Wif  = (const float*)d_in[6];  const float* bif = (const float*)d_in[7];
  const float* Whf  = (const float*)d_in[8];  const float* bhf = (const float*)d_in[9];
  const float* Wig  = (const float*)d_in[10]; const float* big_ = (const float*)d_in[11];
  const float* Whg  = (const float*)d_in[12]; const float* bhg = (const float*)d_in[13];
  const float* Wio  = (const float*)d_in[14]; const float* bio = (const float*)d_in[15];
  const float* Who  = (const float*)d_in[16]; const float* bho = (const float*)d_in[17];
  const float* W_att = (const float*)d_in[18]; const float* b_att = (const float*)d_in[19];
  const float* W_ol  = (const float*)d_in[20]; const float* b_ol  = (const float*)d_in[21];
  const float* W_fc  = (const float*)d_in[22]; const float* b_fc  = (const float*)d_in[23];

  uint8_t* ws = (uint8_t*)d_ws;
  u16* hs       = (u16*)ws;                              // 512*64*512*2 = 32 MiB
  size_t off    = (size_t)33554432;
  u16* wbuf     = (u16*)(ws + off);   off += 6291456;    // 128*64*48*16B = 6 MiB
  float* bias_s = (float*)(ws + off); off += 8192;       // 128*16*4
  u64* hbuf     = (u64*)(ws + off);   off += 262144;     // 2*16384 u64 = 256KB
  float* hlast  = (float*)(ws + off); off += 131072;     // 64*512*4
  u32* slots    = (u32*)(ws + off);                      // 4*64 slots x 64B

  hipMemsetAsync(slots, 0, 16384, stream);               // reset per launch/replay

  stage_weights<<<dim3(NWGW), dim3(64), 0, stream>>>(
      Whr, Whf, Whg, Who, Wir, Wif, Wig, Wio,
      bhr, bhf, bhg, bho, bir, bif, big_, bio, wbuf, bias_s);

  lstm_persist<<<dim3(NBLK), dim3(256), 0, stream>>>(
      words, emb, wbuf, bias_s, hbuf, hs, hlast, slots);

  post_kernel<<<dim3(NB), dim3(256), 0, stream>>>(hlast, hs, W_ol, b_ol, W_att, b_att,
                                                  W_fc, b_fc, (float*)d_out);
}